// Round 11
// baseline (94.470 us; speedup 1.0000x reference)
//
#include <hip/hip_runtime.h>
#include <stdint.h>
#include <math.h>

typedef unsigned int u32;
typedef unsigned long long u64;

#define NN_ 28800
#define MM_ 64
#define BB_ 16
#define XROW_ 25
#define POS_CAP_ 128u
#define BATCH_ 256u
#define XSPAN_ 1579               // floats staged per image row: [21, 1600)
#define RBLK_ 16                  // row blocks per image (6 waves x 3 rows each)
#define FBLK_ 75                  // fill blocks per image (384 anchors each)
#define NPART_ (RBLK_ + FBLK_)    // 91 count-parts per image

struct Keys { u32 k[BB_][4]; };
struct Geo  { int wlo[9], wspan[9], hlo[9], rowbase[10]; float hxv[9], hyv[9]; };

// ---------------- threefry2x32 (JAX-exact), host+device ----------------
__host__ __device__ __forceinline__ u32 rotl32(u32 v, u32 r){ return (v<<r)|(v>>(32u-r)); }

__host__ __device__ __forceinline__ void tf2x32(u32 k0, u32 k1, u32 x0, u32 x1, u32& y0, u32& y1){
  u32 ks2 = k0 ^ k1 ^ 0x1BD11BDAu;
  x0 += k0; x1 += k1;
#define TFR(r) { x0 += x1; x1 = rotl32(x1,(r)); x1 ^= x0; }
  TFR(13) TFR(15) TFR(26) TFR(6)   x0 += k1;  x1 += ks2 + 1u;
  TFR(17) TFR(29) TFR(16) TFR(24)  x0 += ks2; x1 += k0  + 2u;
  TFR(13) TFR(15) TFR(26) TFR(6)   x0 += k0;  x1 += k1  + 3u;
  TFR(17) TFR(29) TFR(16) TFR(24)  x0 += k1;  x1 += ks2 + 4u;
  TFR(13) TFR(15) TFR(26) TFR(6)   x0 += ks2; x1 += k0  + 5u;
#undef TFR
  y0 = x0; y1 = x1;
}

// ---------------- anchors: pure-float, bit-exact vs numpy ----------------
__host__ __device__ __forceinline__ void anchor_hxy(int a, float& hx, float& hy){
  int p = (a >= 6) ? 2 : ((a >= 3) ? 1 : 0);
  int q = a - p*3;
  float sf = (p==0) ? 128.0f : ((p==1) ? 256.0f : 512.0f);
  const float SQH = 0.70710678118654752440f;
  const float SQ2 = 1.41421356237309514547f;
  float cw = (q==0) ? SQH : ((q==1) ? 1.0f : SQ2);
  float ch = (q==0) ? SQ2 : ((q==1) ? 1.0f : SQH);
  hx = (sf*cw) * 0.5f;
  hy = (sf*ch) * 0.5f;
}

__device__ __forceinline__ void anchor_from(int a, int cell,
                                            float& ox1, float& oy1, float& ox2, float& oy2){
  #pragma clang fp contract(off)
  int w = cell & 63;
  int h = cell >> 6;
  float hx, hy; anchor_hxy(a, hx, hy);
  float cx = ((float)w + 0.5f) * 16.0f;
  float cy = ((float)h + 0.5f) * 16.0f;
  float X1 = (cx - hx) / 1024.0f;
  float Y1 = (cy - hy) / 800.0f;
  float X2 = (cx + hx) / 1024.0f;
  float Y2 = (cy + hy) / 800.0f;
  bool valid = (X1 > 0.0f) && (Y1 > 0.0f) && (X2 < 1.0f) && (Y2 < 1.0f);
  ox1 = valid ? X1 : 0.0f;
  oy1 = valid ? Y1 : 0.0f;
  ox2 = valid ? X2 : 0.0f;
  oy2 = valid ? Y2 : 0.0f;
}

__device__ __forceinline__ float iou_of(float bx1,float by1,float bx2,float by2,float ba,
                                        float gx1,float gy1,float gx2,float gy2,float garea){
  #pragma clang fp contract(off)
  float ix1 = fmaxf(bx1,gx1), iy1 = fmaxf(by1,gy1);
  float ix2 = fminf(bx2,gx2), iy2 = fminf(by2,gy2);
  float iw = fmaxf(ix2-ix1, 0.0f), ih = fmaxf(iy2-iy1, 0.0f);
  float inter = iw*ih;
  float den = ba + garea;        // exact reference op order, no FMA
  den = den - inter;
  den = den + 1e-7f;
  return inter / den;
}

// ---------------- K1: row-structured valid pass + invalid fill pass ----------------
__global__ __launch_bounds__(384) void k_main(const float* __restrict__ x, Keys keys, Geo geo,
                                              u64* __restrict__ bestpart,
                                              u32* __restrict__ cnts_part,
                                              u32* __restrict__ rpv, u32* __restrict__ rnv){
  #pragma clang fp contract(off)
  int tid = threadIdx.x;          // 0..383 (6 waves)
  int lane = tid & 63;
  int wid = tid >> 6;
  int bx = blockIdx.x;
  int b = blockIdx.y;

  if (bx < RBLK_){
    // ======== row blocks: valid anchors only, (a,h)-row per wave-iteration ========
    __shared__ float xr[XSPAN_];  // gt j coord c at xr[25j+c]
    for (int t = tid; t < XSPAN_; t += 384) xr[t] = x[b*(MM_*XROW_) + 21 + t];
    __syncthreads();
    float gx1 = xr[25*lane+0], gy1 = xr[25*lane+1], gx2 = xr[25*lane+2], gy2 = xr[25*lane+3];
    float garea = (gx2-gx1)*(gy2-gy1);

    int nrows = geo.rowbase[9];
    u32 cp = 0, cn = 0;
    u64 bk = 0;                   // per-lane (gt) best over this block's rows

    for (int rr = 0; rr < 3; ++rr){
      int r = bx*18 + wid*3 + rr;
      if (r >= nrows) break;
      int a = 0;
      #pragma unroll 8
      for (int t = 0; t < 8; ++t) if (r >= geo.rowbase[a+1]) ++a;
      int h = geo.hlo[a] + (r - geo.rowbase[a]);
      float hx = geo.hxv[a], hy = geo.hyv[a];
      float cy = ((float)h + 0.5f)*16.0f;
      float ay1 = (cy - hy)/800.0f, ay2 = (cy + hy)/800.0f;
      float dy = ay2 - ay1;
      float iy1 = fmaxf(ay1, gy1), iy2 = fminf(ay2, gy2);
      float ihj = fmaxf(iy2 - iy1, 0.0f);
      int wlo = geo.wlo[a], wspan = geo.wspan[a];
      u64 fullm = (wspan >= 64) ? ~0ull : ((1ull << wspan) - 1ull);
      u64 pcm = 0, ncm = 0;
      if (__ballot(ihj != 0.0f) == 0ull){
        ncm = fullm;              // row's y-band misses every gt: iou==0 everywhere
      } else {
        #pragma unroll 2
        for (int k = 0; k < wspan; ++k){
          float cx = ((float)(wlo + k) + 0.5f)*16.0f;
          float bx1 = (cx - hx)/1024.0f, bx2 = (cx + hx)/1024.0f;
          float ix1 = fmaxf(bx1, gx1), ix2 = fminf(bx2, gx2);
          float iw = fmaxf(ix2 - ix1, 0.0f);
          float inter = iw * ihj;
          float areaa = (bx2 - bx1)*dy;
          float den = areaa + garea;   // exact reference op order, no FMA
          den = den - inter;
          den = den + 1e-7f;
          float iou = inter / den;
          u64 pcb = __ballot(iou > 0.7f);    // any gt > FG_T
          u64 ncb = __ballot(iou >= 0.3f);   // none >= BG_T <=> max < BG_T
          if (pcb)  pcm |= 1ull << k;
          if (!ncb) ncm |= 1ull << k;
          u32 ib = __float_as_uint(iou);
          if (ib){
            int i = (h*64 + wlo + k)*9 + a;
            u64 key = ((u64)ib << 32) | (u64)(0xFFFFFFFFu - (u32)i);
            if (key > bk) bk = key;          // smaller i wins ties via ~i
          }
        }
      }
      // phase B for this row: lane = anchor slot
      if (lane < wspan){
        int i = (h*64 + wlo + lane)*9 + a;
        bool pcL = (pcm >> lane) & 1ull;
        bool ncL = (ncm >> lane) & 1ull;
        u32 rp = 0, rn = 0;
        if (pcm){                 // wave-uniform (pos is rare)
          u32 a0,a1; tf2x32(keys.k[b][0], keys.k[b][1], 0u, (u32)i, a0,a1);
          rp = pcL ? ((a0^a1) >> 9) + 1u : 0u;
        }
        if (ncm){
          u32 c0,c1; tf2x32(keys.k[b][2], keys.k[b][3], 0u, (u32)i, c0,c1);
          rn = ncL ? ((c0^c1) >> 9) + 1u : 0u;
        }
        rpv[(size_t)b*NN_ + i] = rp;
        rnv[(size_t)b*NN_ + i] = rn;
      }
      cp += (u32)__popcll(pcm);
      cn += (u32)__popcll(ncm);
    }

    // per-block combine
    __shared__ u64 wl[384];
    __shared__ u32 scnt[12];
    wl[wid*64 + lane] = bk;
    if (lane == 0){ scnt[wid*2+0] = cp; scnt[wid*2+1] = cn; }
    __syncthreads();
    if (tid < 64){
      u64 m = wl[tid];
      #pragma unroll
      for (int w = 1; w < 6; ++w){ u64 v = wl[w*64+tid]; if (v > m) m = v; }
      bestpart[((size_t)(b*RBLK_ + bx))*64 + tid] = m;
    }
    if (tid == 0){
      u32 c0 = 0, c1 = 0;
      #pragma unroll
      for (int w = 0; w < 6; ++w){ c0 += scnt[w*2+0]; c1 += scnt[w*2+1]; }
      cnts_part[(b*NPART_ + bx)*2 + 0] = c0;
      cnts_part[(b*NPART_ + bx)*2 + 1] = c1;
    }
  } else {
    // ======== fill blocks: invalid anchors -> rpv=0, rnv=threefry, count neg ========
    int i = (bx - RBLK_)*384 + tid;           // 75*384 = 28800 exactly
    int a = i % 9, cell = i / 9;
    float ax1,ay1,ax2,ay2;
    anchor_from(a, cell, ax1,ay1,ax2,ay2);
    bool inv = !(ax2 > 0.0f);
    if (inv){
      u32 c0,c1; tf2x32(keys.k[b][2], keys.k[b][3], 0u, (u32)i, c0,c1);
      rpv[(size_t)b*NN_ + i] = 0u;
      rnv[(size_t)b*NN_ + i] = ((c0^c1) >> 9) + 1u;
    }
    __shared__ u32 scnt2[6];
    u64 bal = __ballot(inv);
    if (lane == 0) scnt2[wid] = (u32)__popcll(bal);
    __syncthreads();
    if (tid == 0){
      u32 c1 = 0;
      #pragma unroll
      for (int w = 0; w < 6; ++w) c1 += scnt2[w];
      cnts_part[(b*NPART_ + bx)*2 + 0] = 0u;
      cnts_part[(b*NPART_ + bx)*2 + 1] = c1;
    }
  }
}

// ---------------- K2: fused reduce + forced fixup + selection threshold ----------------
__global__ __launch_bounds__(1024) void k_selfix(const float* __restrict__ x,
                                                 const u64* __restrict__ bestpart,
                                                 const u32* __restrict__ cnts_part,
                                                 Keys keys,
                                                 u32* __restrict__ rpv,
                                                 const u32* __restrict__ rnv,
                                                 u32* __restrict__ selp){
  #pragma clang fp contract(off)
  int cls = blockIdx.x, b = blockIdx.y, tid = threadIdx.x;
  int lane = tid & 63, wid = tid >> 6;   // 16 waves
  int id = b*2 + cls;

  __shared__ float gbox[MM_][4];
  __shared__ float ga[MM_];
  __shared__ u64 red[16][64];
  __shared__ u32 scp[16], scn[16];
  __shared__ u32 fist[64];
  __shared__ float fmx[16][64];
  __shared__ u32 sq[4];
  __shared__ u32 hist[4096];
  __shared__ u32 wt[16], wsuf[16];
  __shared__ u32 bc[2];
  __shared__ u64 L[512];
  __shared__ u32 lc;

  if (tid < 256) gbox[tid>>2][tid&3] = x[(b*MM_ + (tid>>2))*XROW_ + 21 + (tid&3)];
  __syncthreads();
  if (tid < MM_){
    float g0=gbox[tid][0], g1=gbox[tid][1], g2=gbox[tid][2], g3=gbox[tid][3];
    ga[tid] = (g2-g0)*(g3-g1);
  }

  // bestpart reduce: 16 waves, one part each
  red[wid][lane] = bestpart[((size_t)(b*RBLK_ + wid))*64 + lane];

  // candidate count sums over 91 parts
  u32 cp = 0, cn = 0;
  if (tid < NPART_){ cp = cnts_part[(b*NPART_+tid)*2+0]; cn = cnts_part[(b*NPART_+tid)*2+1]; }
  #pragma unroll
  for (int off = 32; off >= 1; off >>= 1){
    cp += (u32)__shfl_xor((int)cp, off, 64);
    cn += (u32)__shfl_xor((int)cn, off, 64);
  }
  if (lane == 0){ scp[wid] = cp; scn[wid] = cn; }
  __syncthreads();

  if (tid < 64){
    u64 mm = red[0][tid];
    #pragma unroll
    for (int w = 1; w < 16; ++w){ u64 v = red[w][tid]; if (v > mm) mm = v; }
    fist[tid] = ((u32)(mm >> 32) != 0u) ? (0xFFFFFFFFu - (u32)mm) : 0xFFFFFFFFu;
  }
  if (tid == 0){
    u32 c0 = 0, c1 = 0;
    for (int w = 0; w < 16; ++w){ c0 += scp[w]; c1 += scn[w]; }
    sq[0] = c0; sq[1] = c1;
  }
  __syncthreads();

  // forced pcflag recompute: was forced anchor already a pos candidate?
  {
    int j = tid & 63, q = tid >> 6;
    float mm = 0.0f;
    u32 fi = fist[j];
    if (fi != 0xFFFFFFFFu){
      float ax1,ay1,ax2,ay2;
      anchor_from((int)(fi % 9), (int)(fi / 9), ax1,ay1,ax2,ay2);
      float aarea = (ax2-ax1)*(ay2-ay1);
      #pragma unroll
      for (int t = 0; t < 4; ++t){
        int j2 = q*4 + t;
        float iou = iou_of(ax1,ay1,ax2,ay2,aarea,
                           gbox[j2][0],gbox[j2][1],gbox[j2][2],gbox[j2][3], ga[j2]);
        mm = fmaxf(mm, iou);
      }
    }
    fmx[q][j] = mm;
  }
  __syncthreads();

  if (tid < 64){
    int j = tid;
    u32 fi = fist[j];
    bool valid = (fi != 0xFFFFFFFFu);
    float mm = fmx[0][j];
    #pragma unroll
    for (int q = 1; q < 16; ++q) mm = fmaxf(mm, fmx[q][j]);
    bool wasc = (mm > 0.7f);                 // == (rpv[fi] != 0 pre-fixup), bit-exact
    bool first = true;
    for (int j2 = 0; j2 < j; ++j2) if (fist[j2] == fi) first = false;
    bool add = valid && !wasc && first;
    u64 bal = __ballot(add);
    if (cls == 0 && valid){                  // pos block: ensure forced anchor in rpv
      u32 a0,a1; tf2x32(keys.k[b][0], keys.k[b][1], 0u, fi, a0,a1);
      rpv[(size_t)b*NN_ + fi] = ((a0^a1) >> 9) + 1u;   // idempotent value
    }
    if (tid == 0) sq[2] = sq[0] + (u32)__popcll(bal);  // posc
  }
  __syncthreads();

  u32 posc = sq[2], negc = sq[1];
  u32 npos = min(posc, POS_CAP_);
  u32 K   = cls ? (BATCH_ - npos) : npos;
  u32 cnt = cls ? negc : posc;
  if (cnt <= K){
    if (tid == 0){ selp[id*2+0] = 0u; selp[id*2+1] = 0xFFFFFFFFu; }
    return;
  }

  const u32* v = (cls ? rnv : rpv) + (size_t)b*NN_;
  const uint4* v4 = (const uint4*)v;
  #pragma unroll
  for (int h = 0; h < 4; ++h) hist[h*1024 + tid] = 0;
  if (tid == 0) lc = 0;
  __syncthreads();
  for (int i2 = tid; i2 < NN_/4; i2 += 1024){
    uint4 q = v4[i2];
    if (q.x) atomicAdd(&hist[(q.x-1u)>>11], 1u);
    if (q.y) atomicAdd(&hist[(q.y-1u)>>11], 1u);
    if (q.z) atomicAdd(&hist[(q.z-1u)>>11], 1u);
    if (q.w) atomicAdd(&hist[(q.w-1u)>>11], 1u);
  }
  __syncthreads();
  u32 s = hist[tid*4+0] + hist[tid*4+1] + hist[tid*4+2] + hist[tid*4+3];
  u32 incl = s;
  #pragma unroll
  for (int off = 1; off < 64; off <<= 1){
    u32 o = (u32)__shfl_down((int)incl, off, 64);
    incl += (lane + off < 64) ? o : 0u;
  }
  if (lane == 0) wt[wid] = incl;
  __syncthreads();
  if (tid < 16){ u32 ss = 0; for (int w = tid+1; w < 16; ++w) ss += wt[w]; wsuf[tid] = ss; }
  __syncthreads();
  u32 excl = incl - s + wsuf[wid];
  if (excl < K && excl + s >= K){
    u32 acc = excl;
    for (int q = 3; q >= 0; --q){
      u32 h = hist[tid*4 + q];
      if (acc + h >= K){ bc[0] = (u32)(tid*4 + q); bc[1] = K - acc; break; }
      acc += h;
    }
  }
  __syncthreads();
  u32 B = bc[0], Kp = bc[1];
  for (int i2 = tid; i2 < NN_/4; i2 += 1024){
    uint4 q = v4[i2];
    #pragma unroll
    for (int c = 0; c < 4; ++c){
      u32 xv = (c==0)?q.x:(c==1)?q.y:(c==2)?q.z:q.w;
      if (xv && ((xv - 1u) >> 11) == B){
        u32 p = atomicAdd(&lc, 1u);
        if (p < 512u) L[p] = ((u64)xv << 32) | (u32)(i2*4 + c);
      }
    }
  }
  __syncthreads();
  u32 n = min(lc, 512u);
  if (tid < (int)n){
    u64 me = L[tid]; u32 mv = (u32)(me >> 32), mi = (u32)me;
    u32 r = 0;
    for (u32 t2 = 0; t2 < n; ++t2){
      u64 o = L[t2]; u32 ov = (u32)(o >> 32), oi = (u32)o;
      r += (ov > mv) || (ov == mv && oi < mi);
    }
    if (r == Kp - 1u){ selp[id*2+0] = mv; selp[id*2+1] = mi; }
  }
}

// ---------------- K3: final cls + offsets (argmax recomputed for selpos only) ----------------
__global__ __launch_bounds__(256) void k_out(const float* __restrict__ x,
                                             const u32* __restrict__ rpv,
                                             const u32* __restrict__ rnv,
                                             const u32* __restrict__ selp,
                                             float* __restrict__ out){
  #pragma clang fp contract(off)
  int b = blockIdx.y, tid = threadIdx.x;
  __shared__ float xr[XSPAN_];
  for (int t = tid; t < XSPAN_; t += 256) xr[t] = x[b*(MM_*XROW_) + 21 + t];
  __syncthreads();
  int i = blockIdx.x*256 + tid;
  if (i >= NN_) return;

  u32 pth = selp[(b*2+0)*2+0], pcut = selp[(b*2+0)*2+1];
  u32 nth = selp[(b*2+1)*2+0], ncut = selp[(b*2+1)*2+1];
  u32 pv = rpv[(size_t)b*NN_+i], nv = rnv[(size_t)b*NN_+i];
  bool selpos = (pv > 0u) && (pv > pth || (pv == pth && (u32)i <= pcut));
  bool selneg = (nv > 0u) && (nv > nth || (nv == nth && (u32)i <= ncut));
  float cls = selpos ? 1.0f : -1.0f;
  if (selneg) cls = 0.0f;

  float tx = 0.0f, ty = 0.0f, tw = 0.0f, th = 0.0f;
  if (selpos){
    int a = i % 9, cell = i / 9;
    float ax1,ay1,ax2,ay2;
    anchor_from(a, cell, ax1,ay1,ax2,ay2);
    float area_a = (ax2-ax1)*(ay2-ay1);
    float best = -1.0f; int bj = 0;
    for (int j = 0; j < MM_; ++j){
      float g0=xr[25*j+0], g1=xr[25*j+1], g2=xr[25*j+2], g3=xr[25*j+3];
      float ix1 = fmaxf(ax1,g0), iy1 = fmaxf(ay1,g1);
      float ix2 = fminf(ax2,g2), iy2 = fminf(ay2,g3);
      float iw = fmaxf(ix2-ix1, 0.0f), ih = fmaxf(iy2-iy1, 0.0f);
      float inter = iw*ih;
      float den = area_a + (g2-g0)*(g3-g1);
      den = den - inter;
      den = den + 1e-7f;
      float iou = inter / den;
      if (iou > best){ best = iou; bj = j; }
    }
    float g0=xr[25*bj+0], g1=xr[25*bj+1], g2=xr[25*bj+2], g3=xr[25*bj+3];
    float wgt = g2-g0, hgt = g3-g1;
    float xcg = (g2+g0)*0.5f, ycg = (g3+g1)*0.5f;
    float wr = ax2-ax1, hr = ay2-ay1;
    float xcr = (ax2+ax1)*0.5f, ycr = (ay2+ay1)*0.5f;
    float wrs = (wr > 0.0f) ? wr : 1.0f;
    float hrs = (hr > 0.0f) ? hr : 1.0f;
    tx = (wgt > 0.0f) ? (xcg - xcr)/wrs : 0.0f;
    ty = (hgt > 0.0f) ? (ycg - ycr)/hrs : 0.0f;
    tw = (wgt > 0.0f) ? logf(wgt/wrs) : 0.0f;
    th = (hgt > 0.0f) ? logf(hgt/hrs) : 0.0f;
  }
  float* o = out + (size_t)((size_t)b*NN_+i)*5;
  o[0] = cls; o[1] = tx; o[2] = ty; o[3] = tw; o[4] = th;
}

extern "C" void kernel_launch(void* const* d_in, const int* in_sizes, int n_in,
                              void* d_out, int out_size, void* d_ws, size_t ws_size,
                              hipStream_t stream) {
  const float* x = (const float*)d_in[0];
  float* out = (float*)d_out;
  char* ws = (char*)d_ws;

  // ws layout — nothing needs pre-zeroing (all buffers fully overwritten each launch)
  u32* selp      = (u32*)(ws + 0);            // 256 B
  u64* bestpart  = (u64*)(ws + 512);          // 16*16*64*8 = 131,072 B
  u32* cnts_part = (u32*)(ws + 131584);       // 16*91*2*4 = 11,648 B
  u32* rpv       = (u32*)(ws + 143360);       // 1,843,200 B
  u32* rnv       = (u32*)(ws + 1986560);      // 1,843,200 B (end ≈ 3.8 MB)
  (void)ws_size; (void)in_sizes; (void)n_in; (void)out_size;

  // host-side JAX key derivation (partitionable threefry), deterministic
  Keys keys;
  for (int b = 0; b < BB_; ++b){
    u32 r0, r1;
    tf2x32(0u, 42u, 0u, (u32)b, r0, r1);
    tf2x32(r0, r1, 0u, 0u, keys.k[b][0], keys.k[b][1]);
    tf2x32(r0, r1, 0u, 1u, keys.k[b][2], keys.k[b][3]);
  }

  // host-side validity geometry — replicates device float comparisons exactly
  Geo geo;
  int rb = 0;
  for (int a = 0; a < 9; ++a){
    float hx, hy; anchor_hxy(a, hx, hy);
    int wlo = 64, whi = -1;
    for (int w = 0; w < 64; ++w){
      float cx = ((float)w + 0.5f)*16.0f;
      float X1 = (cx - hx)/1024.0f, X2 = (cx + hx)/1024.0f;
      if (X1 > 0.0f && X2 < 1.0f){ if (w < wlo) wlo = w; if (w > whi) whi = w; }
    }
    int hlo = 50, hhi = -1;
    for (int h = 0; h < 50; ++h){
      float cy = ((float)h + 0.5f)*16.0f;
      float Y1 = (cy - hy)/800.0f, Y2 = (cy + hy)/800.0f;
      if (Y1 > 0.0f && Y2 < 1.0f){ if (h < hlo) hlo = h; if (h > hhi) hhi = h; }
    }
    geo.wlo[a] = wlo; geo.wspan[a] = (whi >= wlo) ? (whi - wlo + 1) : 0;
    geo.hlo[a] = hlo;
    geo.hxv[a] = hx;  geo.hyv[a] = hy;
    geo.rowbase[a] = rb;
    rb += (hhi >= hlo && whi >= wlo) ? (hhi - hlo + 1) : 0;
  }
  geo.rowbase[9] = rb;   // total rows (≈274, fits 16 blocks × 6 waves × 3 rows = 288)

  k_main  <<<dim3(NPART_, BB_), 384, 0, stream>>>(x, keys, geo, bestpart, cnts_part, rpv, rnv);
  k_selfix<<<dim3(2, BB_), 1024, 0, stream>>>(x, bestpart, cnts_part, keys, rpv, rnv, selp);
  k_out   <<<dim3(113, BB_), 256, 0, stream>>>(x, rpv, rnv, selp, out);
}

// Round 12
// 72.202 us; speedup vs baseline: 1.3084x; 1.3084x over previous
//
#include <hip/hip_runtime.h>
#include <stdint.h>
#include <math.h>

typedef unsigned int u32;
typedef unsigned long long u64;

#define NN_ 28800
#define MM_ 64
#define BB_ 16
#define XROW_ 25
#define POS_CAP_ 128u
#define BATCH_ 256u
#define NBLK_ 75                  // k_main blocks per image (384 anchors each)
#define XSPAN_ 1579               // floats staged per image row: [21, 1600)

struct Keys { u32 k[BB_][4]; };

// ---------------- threefry2x32 (JAX-exact), host+device ----------------
__host__ __device__ __forceinline__ u32 rotl32(u32 v, u32 r){ return (v<<r)|(v>>(32u-r)); }

__host__ __device__ __forceinline__ void tf2x32(u32 k0, u32 k1, u32 x0, u32 x1, u32& y0, u32& y1){
  u32 ks2 = k0 ^ k1 ^ 0x1BD11BDAu;
  x0 += k0; x1 += k1;
#define TFR(r) { x0 += x1; x1 = rotl32(x1,(r)); x1 ^= x0; }
  TFR(13) TFR(15) TFR(26) TFR(6)   x0 += k1;  x1 += ks2 + 1u;
  TFR(17) TFR(29) TFR(16) TFR(24)  x0 += ks2; x1 += k0  + 2u;
  TFR(13) TFR(15) TFR(26) TFR(6)   x0 += k0;  x1 += k1  + 3u;
  TFR(17) TFR(29) TFR(16) TFR(24)  x0 += k1;  x1 += ks2 + 4u;
  TFR(13) TFR(15) TFR(26) TFR(6)   x0 += ks2; x1 += k0  + 5u;
#undef TFR
  y0 = x0; y1 = x1;
}

// ---------------- anchors: pure-float, bit-exact vs numpy ----------------
__device__ __forceinline__ void anchor_from(int a, int cell,
                                            float& ox1, float& oy1, float& ox2, float& oy2){
  #pragma clang fp contract(off)
  int w = cell & 63;
  int h = cell >> 6;
  int p = (a >= 6) ? 2 : ((a >= 3) ? 1 : 0);
  int q = a - p*3;
  float sf = (p==0) ? 128.0f : ((p==1) ? 256.0f : 512.0f);
  const float SQH = 0.70710678118654752440f;
  const float SQ2 = 1.41421356237309514547f;
  float cw = (q==0) ? SQH : ((q==1) ? 1.0f : SQ2);
  float ch = (q==0) ? SQ2 : ((q==1) ? 1.0f : SQH);
  float hx = (sf*cw) * 0.5f;
  float hy = (sf*ch) * 0.5f;
  float cx = ((float)w + 0.5f) * 16.0f;
  float cy = ((float)h + 0.5f) * 16.0f;
  float X1 = (cx - hx) / 1024.0f;
  float Y1 = (cy - hy) / 800.0f;
  float X2 = (cx + hx) / 1024.0f;
  float Y2 = (cy + hy) / 800.0f;
  bool valid = (X1 > 0.0f) && (Y1 > 0.0f) && (X2 < 1.0f) && (Y2 < 1.0f);
  ox1 = valid ? X1 : 0.0f;
  oy1 = valid ? Y1 : 0.0f;
  ox2 = valid ? X2 : 0.0f;
  oy2 = valid ? Y2 : 0.0f;
}

__device__ __forceinline__ float rdlane(float v, int k){
  return __int_as_float(__builtin_amdgcn_readlane(__float_as_int(v), k));
}

__device__ __forceinline__ float iou_of(float bx1,float by1,float bx2,float by2,float ba,
                                        float gx1,float gy1,float gx2,float gy2,float garea){
  #pragma clang fp contract(off)
  float ix1 = fmaxf(bx1,gx1), iy1 = fmaxf(by1,gy1);
  float ix2 = fminf(bx2,gx2), iy2 = fminf(by2,gy2);
  float iw = fmaxf(ix2-ix1, 0.0f), ih = fmaxf(iy2-iy1, 0.0f);
  float inter = iw*ih;
  float den = ba + garea;        // exact reference op order, no FMA
  den = den - inter;
  den = den + 1e-7f;
  return inter / den;
}

// ---------------- K1: transposed (lane = gt); coalesced x staging; 6 waves/block ----------------
__global__ __launch_bounds__(384) void k_main(const float* __restrict__ x, Keys keys,
                                              u64* __restrict__ bestpart,
                                              u32* __restrict__ cnts_part,
                                              u32* __restrict__ rpv, u32* __restrict__ rnv){
  #pragma clang fp contract(off)
  int tid = threadIdx.x;          // 0..383 (6 waves)
  int lane = tid & 63;
  int wid = tid >> 6;
  int bx = blockIdx.x;
  int b = blockIdx.y;
  int cbase = (bx*6 + wid)*64;    // this wave's 64-anchor chunk

  __shared__ float xr[XSPAN_];    // x[b, :, 21:1600) -> gt j coord c at xr[25j+c]
  for (int t = tid; t < XSPAN_; t += 384) xr[t] = x[b*(MM_*XROW_) + 21 + t];
  __syncthreads();

  // lane j holds gt j in registers (conflict-free: 25*j mod 32 all distinct)
  float gx1 = xr[25*lane+0], gy1 = xr[25*lane+1], gx2 = xr[25*lane+2], gy2 = xr[25*lane+3];
  float garea = (gx2-gx1)*(gy2-gy1);

  // lane k holds anchor (cbase+k)'s box
  int ia = cbase + lane;
  int a = ia % 9, cell = ia / 9;
  float ax1,ay1,ax2,ay2;
  anchor_from(a, cell, ax1,ay1,ax2,ay2);
  float aarea = (ax2-ax1)*(ay2-ay1);

  u64 valid_mask = __ballot(ax2 > 0.0f);
  u64 pcbits = 0;
  u64 ncbits = ~valid_mask;       // invalid anchors: miou==0 -> neg cand, not pos
  u64 bk = 0;                     // per-lane: best (iou,~i) for gt=lane

  u64 vm = valid_mask;
  while (vm){
    int k1 = __ffsll((unsigned long long)vm) - 1; vm &= vm - 1ull;
    int k2 = vm ? __ffsll((unsigned long long)vm) - 1 : k1; vm &= vm - 1ull;
    int k3 = vm ? __ffsll((unsigned long long)vm) - 1 : k1; vm &= vm - 1ull;
    int k4 = vm ? __ffsll((unsigned long long)vm) - 1 : k1; vm &= vm - 1ull;
    // four independent chains -> ILP (duplicates are idempotent)
    float c1x1=rdlane(ax1,k1), c1y1=rdlane(ay1,k1), c1x2=rdlane(ax2,k1), c1y2=rdlane(ay2,k1), c1a=rdlane(aarea,k1);
    float c2x1=rdlane(ax1,k2), c2y1=rdlane(ay1,k2), c2x2=rdlane(ax2,k2), c2y2=rdlane(ay2,k2), c2a=rdlane(aarea,k2);
    float c3x1=rdlane(ax1,k3), c3y1=rdlane(ay1,k3), c3x2=rdlane(ax2,k3), c3y2=rdlane(ay2,k3), c3a=rdlane(aarea,k3);
    float c4x1=rdlane(ax1,k4), c4y1=rdlane(ay1,k4), c4x2=rdlane(ax2,k4), c4y2=rdlane(ay2,k4), c4a=rdlane(aarea,k4);
    float i1 = iou_of(c1x1,c1y1,c1x2,c1y2,c1a, gx1,gy1,gx2,gy2,garea);
    float i2 = iou_of(c2x1,c2y1,c2x2,c2y2,c2a, gx1,gy1,gx2,gy2,garea);
    float i3 = iou_of(c3x1,c3y1,c3x2,c3y2,c3a, gx1,gy1,gx2,gy2,garea);
    float i4 = iou_of(c4x1,c4y1,c4x2,c4y2,c4a, gx1,gy1,gx2,gy2,garea);
    u64 p1 = __ballot(i1 > 0.7f), n1 = __ballot(i1 >= 0.3f);
    u64 p2 = __ballot(i2 > 0.7f), n2 = __ballot(i2 >= 0.3f);
    u64 p3 = __ballot(i3 > 0.7f), n3 = __ballot(i3 >= 0.3f);
    u64 p4 = __ballot(i4 > 0.7f), n4 = __ballot(i4 >= 0.3f);
    if (p1)  pcbits |= 1ull << k1;
    if (!n1) ncbits |= 1ull << k1;
    if (p2)  pcbits |= 1ull << k2;
    if (!n2) ncbits |= 1ull << k2;
    if (p3)  pcbits |= 1ull << k3;
    if (!n3) ncbits |= 1ull << k3;
    if (p4)  pcbits |= 1ull << k4;
    if (!n4) ncbits |= 1ull << k4;
    u32 q1 = __float_as_uint(i1), q2 = __float_as_uint(i2);
    u32 q3 = __float_as_uint(i3), q4 = __float_as_uint(i4);
    u64 key1 = ((u64)q1 << 32) | (u64)(0xFFFFFFFFu - (u32)(cbase + k1));
    u64 key2 = ((u64)q2 << 32) | (u64)(0xFFFFFFFFu - (u32)(cbase + k2));
    u64 key3 = ((u64)q3 << 32) | (u64)(0xFFFFFFFFu - (u32)(cbase + k3));
    u64 key4 = ((u64)q4 << 32) | (u64)(0xFFFFFFFFu - (u32)(cbase + k4));
    if (q1 && key1 > bk) bk = key1;    // ascending k order: smaller i wins ties via ~i
    if (q2 && key2 > bk) bk = key2;
    if (q3 && key3 > bk) bk = key3;
    if (q4 && key4 > bk) bk = key4;
  }

  // ---- phase B: lane = anchor; threefry + rank values ----
  int i = cbase + lane;
  bool pc = (pcbits >> lane) & 1ull;
  bool nc = (ncbits >> lane) & 1ull;
  u32 rp = 0, rn = 0;
  if (pcbits){                    // wave-uniform skip (pos is rare)
    u32 a0,a1;
    tf2x32(keys.k[b][0], keys.k[b][1], 0u, (u32)i, a0,a1);
    rp = pc ? ((a0^a1) >> 9) + 1u : 0u;
  }
  if (ncbits){
    u32 c0,c1;
    tf2x32(keys.k[b][2], keys.k[b][3], 0u, (u32)i, c0,c1);
    rn = nc ? ((c0^c1) >> 9) + 1u : 0u;
  }
  rpv[b*NN_+i] = rp;
  rnv[b*NN_+i] = rn;

  // ---- per-block combine + plain coalesced stores (no atomics, no pre-zero) ----
  __shared__ u64 wl[384];
  __shared__ u32 scnt[12];
  wl[wid*64 + lane] = bk;
  if (lane == 0){ scnt[wid*2+0] = (u32)__popcll(pcbits); scnt[wid*2+1] = (u32)__popcll(ncbits); }
  __syncthreads();
  if (tid < 64){
    u64 m = wl[tid];
    #pragma unroll
    for (int w = 1; w < 6; ++w){ u64 v = wl[w*64+tid]; if (v > m) m = v; }
    bestpart[((size_t)(b*NBLK_ + bx))*64 + tid] = m;
  }
  if (tid == 0){
    u32 c0 = 0, c1 = 0;
    #pragma unroll
    for (int w = 0; w < 6; ++w){ c0 += scnt[w*2+0]; c1 += scnt[w*2+1]; }
    cnts_part[(b*NBLK_ + bx)*2 + 0] = c0;
    cnts_part[(b*NBLK_ + bx)*2 + 1] = c1;
  }
}

// ---------------- K2: fused reduce + forced fixup + selection threshold ----------------
__global__ __launch_bounds__(1024) void k_selfix(const float* __restrict__ x,
                                                 const u64* __restrict__ bestpart,
                                                 const u32* __restrict__ cnts_part,
                                                 Keys keys,
                                                 u32* __restrict__ rpv,
                                                 const u32* __restrict__ rnv,
                                                 u32* __restrict__ selp){
  #pragma clang fp contract(off)
  int cls = blockIdx.x, b = blockIdx.y, tid = threadIdx.x;
  int lane = tid & 63, wid = tid >> 6;   // 16 waves
  int id = b*2 + cls;

  __shared__ float gbox[MM_][4];
  __shared__ float ga[MM_];
  __shared__ u64 red[16][64];
  __shared__ u32 scp[16], scn[16];
  __shared__ u32 fist[64];
  __shared__ float fmx[16][64];
  __shared__ u32 sq[4];
  __shared__ u32 hist[4096];
  __shared__ u32 wt[16], wsuf[16];
  __shared__ u32 bc[2];
  __shared__ u64 L[512];
  __shared__ u32 lc;

  if (tid < 256) gbox[tid>>2][tid&3] = x[(b*MM_ + (tid>>2))*XROW_ + 21 + (tid&3)];
  __syncthreads();
  if (tid < MM_){
    float g0=gbox[tid][0], g1=gbox[tid][1], g2=gbox[tid][2], g3=gbox[tid][3];
    ga[tid] = (g2-g0)*(g3-g1);
  }

  // bestpart reduce (16-way parallel over parts)
  u64 m = 0;
  for (int blk = wid; blk < NBLK_; blk += 16){
    u64 v = bestpart[((size_t)(b*NBLK_ + blk))*64 + lane];
    if (v > m) m = v;
  }
  red[wid][lane] = m;

  // candidate count sums
  u32 cp = 0, cn = 0;
  if (tid < NBLK_){ cp = cnts_part[(b*NBLK_+tid)*2+0]; cn = cnts_part[(b*NBLK_+tid)*2+1]; }
  #pragma unroll
  for (int off = 32; off >= 1; off >>= 1){
    cp += (u32)__shfl_xor((int)cp, off, 64);
    cn += (u32)__shfl_xor((int)cn, off, 64);
  }
  if (lane == 0){ scp[wid] = cp; scn[wid] = cn; }
  __syncthreads();

  if (tid < 64){
    u64 mm = red[0][tid];
    #pragma unroll
    for (int w = 1; w < 16; ++w){ u64 v = red[w][tid]; if (v > mm) mm = v; }
    fist[tid] = ((u32)(mm >> 32) != 0u) ? (0xFFFFFFFFu - (u32)mm) : 0xFFFFFFFFu;
  }
  if (tid == 0){
    u32 c0 = 0, c1 = 0;
    for (int w = 0; w < 16; ++w){ c0 += scp[w]; c1 += scn[w]; }
    sq[0] = c0; sq[1] = c1;
  }
  __syncthreads();

  // forced pcflag recompute: was forced anchor already a pos candidate?
  {
    int j = tid & 63, q = tid >> 6;
    float mm = 0.0f;
    u32 fi = fist[j];
    if (fi != 0xFFFFFFFFu){
      float ax1,ay1,ax2,ay2;
      anchor_from((int)(fi % 9), (int)(fi / 9), ax1,ay1,ax2,ay2);
      float aarea = (ax2-ax1)*(ay2-ay1);
      #pragma unroll
      for (int t = 0; t < 4; ++t){
        int j2 = q*4 + t;
        float iou = iou_of(ax1,ay1,ax2,ay2,aarea,
                           gbox[j2][0],gbox[j2][1],gbox[j2][2],gbox[j2][3], ga[j2]);
        mm = fmaxf(mm, iou);
      }
    }
    fmx[q][j] = mm;
  }
  __syncthreads();

  if (tid < 64){
    int j = tid;
    u32 fi = fist[j];
    bool valid = (fi != 0xFFFFFFFFu);
    float mm = fmx[0][j];
    #pragma unroll
    for (int q = 1; q < 16; ++q) mm = fmaxf(mm, fmx[q][j]);
    bool wasc = (mm > 0.7f);                 // == (rpv[fi] != 0 pre-fixup), bit-exact
    bool first = true;
    for (int j2 = 0; j2 < j; ++j2) if (fist[j2] == fi) first = false;
    bool add = valid && !wasc && first;
    u64 bal = __ballot(add);
    if (cls == 0 && valid){                  // pos block: ensure forced anchor in rpv
      u32 a0,a1; tf2x32(keys.k[b][0], keys.k[b][1], 0u, fi, a0,a1);
      rpv[(size_t)b*NN_ + fi] = ((a0^a1) >> 9) + 1u;   // idempotent value
    }
    if (tid == 0) sq[2] = sq[0] + (u32)__popcll(bal);  // posc
  }
  __syncthreads();

  u32 posc = sq[2], negc = sq[1];
  u32 npos = min(posc, POS_CAP_);
  u32 K   = cls ? (BATCH_ - npos) : npos;
  u32 cnt = cls ? negc : posc;
  if (cnt <= K){
    if (tid == 0){ selp[id*2+0] = 0u; selp[id*2+1] = 0xFFFFFFFFu; }
    return;
  }

  const u32* v = (cls ? rnv : rpv) + (size_t)b*NN_;
  const uint4* v4 = (const uint4*)v;
  #pragma unroll
  for (int h = 0; h < 4; ++h) hist[h*1024 + tid] = 0;
  if (tid == 0) lc = 0;
  __syncthreads();
  for (int i2 = tid; i2 < NN_/4; i2 += 1024){
    uint4 q = v4[i2];
    if (q.x) atomicAdd(&hist[(q.x-1u)>>11], 1u);
    if (q.y) atomicAdd(&hist[(q.y-1u)>>11], 1u);
    if (q.z) atomicAdd(&hist[(q.z-1u)>>11], 1u);
    if (q.w) atomicAdd(&hist[(q.w-1u)>>11], 1u);
  }
  __syncthreads();
  u32 s = hist[tid*4+0] + hist[tid*4+1] + hist[tid*4+2] + hist[tid*4+3];
  u32 incl = s;
  #pragma unroll
  for (int off = 1; off < 64; off <<= 1){
    u32 o = (u32)__shfl_down((int)incl, off, 64);
    incl += (lane + off < 64) ? o : 0u;
  }
  if (lane == 0) wt[wid] = incl;
  __syncthreads();
  if (tid < 16){ u32 ss = 0; for (int w = tid+1; w < 16; ++w) ss += wt[w]; wsuf[tid] = ss; }
  __syncthreads();
  u32 excl = incl - s + wsuf[wid];
  if (excl < K && excl + s >= K){
    u32 acc = excl;
    for (int q = 3; q >= 0; --q){
      u32 h = hist[tid*4 + q];
      if (acc + h >= K){ bc[0] = (u32)(tid*4 + q); bc[1] = K - acc; break; }
      acc += h;
    }
  }
  __syncthreads();
  u32 B = bc[0], Kp = bc[1];
  for (int i2 = tid; i2 < NN_/4; i2 += 1024){
    uint4 q = v4[i2];
    #pragma unroll
    for (int c = 0; c < 4; ++c){
      u32 xv = (c==0)?q.x:(c==1)?q.y:(c==2)?q.z:q.w;
      if (xv && ((xv - 1u) >> 11) == B){
        u32 p = atomicAdd(&lc, 1u);
        if (p < 512u) L[p] = ((u64)xv << 32) | (u32)(i2*4 + c);
      }
    }
  }
  __syncthreads();
  u32 n = min(lc, 512u);
  if (tid < (int)n){
    u64 me = L[tid]; u32 mv = (u32)(me >> 32), mi = (u32)me;
    u32 r = 0;
    for (u32 t2 = 0; t2 < n; ++t2){
      u64 o = L[t2]; u32 ov = (u32)(o >> 32), oi = (u32)o;
      r += (ov > mv) || (ov == mv && oi < mi);
    }
    if (r == Kp - 1u){ selp[id*2+0] = mv; selp[id*2+1] = mi; }
  }
}

// ---------------- K3: final cls + offsets; no staging; LDS-coalesced float4 output ----------------
__global__ __launch_bounds__(256) void k_out(const float* __restrict__ x,
                                             const u32* __restrict__ rpv,
                                             const u32* __restrict__ rnv,
                                             const u32* __restrict__ selp,
                                             float* __restrict__ out){
  #pragma clang fp contract(off)
  int b = blockIdx.y, tid = threadIdx.x;
  int i0 = blockIdx.x*256;
  int i = i0 + tid;
  __shared__ float L[1280];       // 256 threads x 5 outputs (stride-5: bank-conflict-free)

  if (i < NN_){
    u32 pth = selp[(b*2+0)*2+0], pcut = selp[(b*2+0)*2+1];
    u32 nth = selp[(b*2+1)*2+0], ncut = selp[(b*2+1)*2+1];
    u32 pv = rpv[(size_t)b*NN_+i], nv = rnv[(size_t)b*NN_+i];
    bool selpos = (pv > 0u) && (pv > pth || (pv == pth && (u32)i <= pcut));
    bool selneg = (nv > 0u) && (nv > nth || (nv == nth && (u32)i <= ncut));
    float cls = selpos ? 1.0f : -1.0f;
    if (selneg) cls = 0.0f;

    float tx = 0.0f, ty = 0.0f, tw = 0.0f, th = 0.0f;
    if (selpos){                  // ~0.9% of threads; gt reads are wave-uniform -> broadcast, L2-hot
      int a = i % 9, cell = i / 9;
      float ax1,ay1,ax2,ay2;
      anchor_from(a, cell, ax1,ay1,ax2,ay2);
      float area_a = (ax2-ax1)*(ay2-ay1);
      float best = -1.0f; int bj = 0;
      for (int j = 0; j < MM_; ++j){
        const float* gp = x + (b*MM_ + j)*XROW_ + 21;
        float g0=gp[0], g1=gp[1], g2=gp[2], g3=gp[3];
        float ix1 = fmaxf(ax1,g0), iy1 = fmaxf(ay1,g1);
        float ix2 = fminf(ax2,g2), iy2 = fminf(ay2,g3);
        float iw = fmaxf(ix2-ix1, 0.0f), ih = fmaxf(iy2-iy1, 0.0f);
        float inter = iw*ih;
        float den = area_a + (g2-g0)*(g3-g1);
        den = den - inter;
        den = den + 1e-7f;
        float iou = inter / den;
        if (iou > best){ best = iou; bj = j; }
      }
      const float* gp = x + (b*MM_ + bj)*XROW_ + 21;
      float g0=gp[0], g1=gp[1], g2=gp[2], g3=gp[3];
      float wgt = g2-g0, hgt = g3-g1;
      float xcg = (g2+g0)*0.5f, ycg = (g3+g1)*0.5f;
      float wr = ax2-ax1, hr = ay2-ay1;
      float xcr = (ax2+ax1)*0.5f, ycr = (ay2+ay1)*0.5f;
      float wrs = (wr > 0.0f) ? wr : 1.0f;
      float hrs = (hr > 0.0f) ? hr : 1.0f;
      tx = (wgt > 0.0f) ? (xcg - xcr)/wrs : 0.0f;
      ty = (hgt > 0.0f) ? (ycg - ycr)/hrs : 0.0f;
      tw = (wgt > 0.0f) ? logf(wgt/wrs) : 0.0f;
      th = (hgt > 0.0f) ? logf(hgt/hrs) : 0.0f;
    }
    L[tid*5+0] = cls; L[tid*5+1] = tx; L[tid*5+2] = ty; L[tid*5+3] = tw; L[tid*5+4] = th;
  }
  __syncthreads();
  int nval = NN_ - i0; if (nval > 256) nval = 256;   // multiple of 4 always (28800 % 256 = 128)
  int nv4 = (nval*5) >> 2;
  float4* o4 = (float4*)(out + ((size_t)b*NN_ + i0)*5);
  for (int t = tid; t < nv4; t += 256) o4[t] = *(float4*)&L[t*4];
}

extern "C" void kernel_launch(void* const* d_in, const int* in_sizes, int n_in,
                              void* d_out, int out_size, void* d_ws, size_t ws_size,
                              hipStream_t stream) {
  const float* x = (const float*)d_in[0];
  float* out = (float*)d_out;
  char* ws = (char*)d_ws;

  // ws layout — nothing needs pre-zeroing (all buffers fully overwritten each launch)
  u32* selp      = (u32*)(ws + 0);            // 256 B
  u64* bestpart  = (u64*)(ws + 512);          // 16*75*64*8 = 614,400 B
  u32* cnts_part = (u32*)(ws + 614912);       // 16*75*2*4 = 9,600 B
  u32* rpv       = (u32*)(ws + 624640);       // 1,843,200 B
  u32* rnv       = (u32*)(ws + 2467840);      // 1,843,200 B (end ≈ 4.31 MB)
  (void)ws_size; (void)in_sizes; (void)n_in; (void)out_size;

  // host-side JAX key derivation (partitionable threefry), deterministic
  Keys keys;
  for (int b = 0; b < BB_; ++b){
    u32 r0, r1;
    tf2x32(0u, 42u, 0u, (u32)b, r0, r1);
    tf2x32(r0, r1, 0u, 0u, keys.k[b][0], keys.k[b][1]);
    tf2x32(r0, r1, 0u, 1u, keys.k[b][2], keys.k[b][3]);
  }

  k_main  <<<dim3(NBLK_, BB_), 384, 0, stream>>>(x, keys, bestpart, cnts_part, rpv, rnv);
  k_selfix<<<dim3(2, BB_), 1024, 0, stream>>>(x, bestpart, cnts_part, keys, rpv, rnv, selp);
  k_out   <<<dim3(113, BB_), 256, 0, stream>>>(x, rpv, rnv, selp, out);
}